// Round 8
// baseline (628.774 us; speedup 1.0000x reference)
//
#include <hip/hip_runtime.h>
#include <math.h>
#include <stdint.h>

typedef __attribute__((ext_vector_type(8))) short short8;
typedef __attribute__((ext_vector_type(4))) float f32x4;
typedef __attribute__((ext_vector_type(4))) unsigned int u32x4;

#define SCALE   30.0f
#define MARGIN  0.5f
#define COS_M   0.8775825618903728f   // cos(0.5)
#define SIN_M   0.4794255386042030f   // sin(0.5)
#define THRESH  (-0.8775825618903728f)

constexpr int Bsz = 256;
constexpr int Dd  = 512;
constexpr int Cc  = 100000;
constexpr int NT  = 782;              // ceil(100000/128) n-tiles (last has 32 valid rows)
constexpr int KT  = 16;               // 512/32 k-steps
constexpr int TILE_EL   = 4096;       // 128 rows x 32 el, one k-step image (8 KB)
constexpr int COMP_TILE = KT * TILE_EL; // 65536 el per (tile, component)

// ---- bf16 helpers (RNE, bit-exact standard bf16) ----
__device__ __forceinline__ unsigned short f2bf(float x) {
    unsigned int u = __float_as_uint(x);
    u += 0x7fffu + ((u >> 16) & 1u);
    return (unsigned short)(u >> 16);
}
__device__ __forceinline__ float bf2f(unsigned short h) {
    return __uint_as_float(((unsigned int)h) << 16);
}

#define GLL16(gptr, lptr)                                                              \
    __builtin_amdgcn_global_load_lds(                                                  \
        (const __attribute__((address_space(1))) unsigned int*)(gptr),                 \
        (__attribute__((address_space(3))) unsigned int*)(lptr), 16, 0, 0)

// swizzled in-tile element offset for (row rr in 0..127, chunk ch in 0..3)
// write-side permutation == read-side permutation (involution), rule #21
__device__ __forceinline__ int swz_off(int rr, int ch) {
    return rr * 32 + ((ch ^ ((rr >> 1) & 3)) * 8);
}

// split a,b into packed bf16 hi words and lo words (lo = RNE(x - hi))
__device__ __forceinline__ void split2(float a, float b, unsigned int& hp, unsigned int& lp) {
    unsigned short h0 = f2bf(a), h1 = f2bf(b);
    unsigned short l0 = f2bf(a - bf2f(h0));
    unsigned short l1 = f2bf(b - bf2f(h1));
    hp = (unsigned int)h0 | ((unsigned int)h1 << 16);
    lp = (unsigned int)l0 | ((unsigned int)l1 << 16);
}

// ---------------- Kernel 1: W -> inv_w + fp32 copy (optional) + pre-swizzled bf16 hi/lo;
// ----------------           blocks 0..63 additionally normalize+split the 256 feat rows ----
__global__ __launch_bounds__(256) void prep_kernel(
    const float* __restrict__ W, const float* __restrict__ F,
    float* __restrict__ inv_w, float* __restrict__ w_copy,   // w_copy nullptr in fallback
    unsigned short* __restrict__ whM, unsigned short* __restrict__ wlM,
    unsigned short* __restrict__ whL, unsigned short* __restrict__ wlL,
    unsigned short* __restrict__ Ah,  unsigned short* __restrict__ Al)
{
    const int wid = threadIdx.x >> 6, lane = threadIdx.x & 63;
    const int tk = lane >> 2, ch = lane & 3;        // lane's octet: k = lane*8 = tk*32 + ch*8

    {   // ---- weight part: 4 rows per block (grid = Cc/4 exactly) ----
        int row = blockIdx.x * 4 + wid;
        const float* src = W + (size_t)row * Dd + lane * 8;
        f32x4 v0 = __builtin_nontemporal_load((const f32x4*)src);     // nt: raw W never re-read
        f32x4 v1 = __builtin_nontemporal_load((const f32x4*)src + 1);
        float v[8] = {v0.x, v0.y, v0.z, v0.w, v1.x, v1.y, v1.z, v1.w};

        float s = 0.f;
        #pragma unroll
        for (int p = 0; p < 8; ++p) s += v[p] * v[p];
        #pragma unroll
        for (int off = 32; off >= 1; off >>= 1) s += __shfl_xor(s, off, 64);
        if (lane == 0) inv_w[row] = 1.0f / sqrtf(s);

        if (w_copy) {
            f32x4* dst = (f32x4*)(w_copy + (size_t)row * Dd + lane * 8);
            __builtin_nontemporal_store(v0, dst);   // nt: fp32 copy never re-read
            __builtin_nontemporal_store(v1, dst + 1);
        }

        unsigned int hp[4], lp[4];
        #pragma unroll
        for (int p = 0; p < 4; ++p) split2(v[2*p], v[2*p+1], hp[p], lp[p]);

        int tn = row >> 7, rr = row & 127;
        size_t off = (size_t)tk * TILE_EL + swz_off(rr, ch);
        unsigned short* ph = (tn == NT-1) ? whL : whM + (size_t)tn * COMP_TILE;
        unsigned short* pl = (tn == NT-1) ? wlL : wlM + (size_t)tn * COMP_TILE;
        *(u32x4*)(ph + off) = u32x4{hp[0], hp[1], hp[2], hp[3]};  // cached: GEMM re-reads
        *(u32x4*)(pl + off) = u32x4{lp[0], lp[1], lp[2], lp[3]};
    }

    if (blockIdx.x < Bsz / 4) {   // ---- feature part: normalize + split ----
        int row = blockIdx.x * 4 + wid;
        const float* src = F + (size_t)row * Dd + lane * 8;
        f32x4 v0 = __builtin_nontemporal_load((const f32x4*)src);     // read exactly once
        f32x4 v1 = __builtin_nontemporal_load((const f32x4*)src + 1);
        float v[8] = {v0.x, v0.y, v0.z, v0.w, v1.x, v1.y, v1.z, v1.w};

        float s = 0.f;
        #pragma unroll
        for (int p = 0; p < 8; ++p) s += v[p] * v[p];
        #pragma unroll
        for (int off = 32; off >= 1; off >>= 1) s += __shfl_xor(s, off, 64);
        float inv = 1.0f / sqrtf(s);

        unsigned int hp[4], lp[4];
        #pragma unroll
        for (int p = 0; p < 4; ++p) split2(v[2*p] * inv, v[2*p+1] * inv, hp[p], lp[p]);

        int tm = row >> 7, rr = row & 127;
        size_t off = ((size_t)(tm * KT + tk)) * TILE_EL + swz_off(rr, ch);
        *(u32x4*)(Ah + off) = u32x4{hp[0], hp[1], hp[2], hp[3]};
        *(u32x4*)(Al + off) = u32x4{lp[0], lp[1], lp[2], lp[3]};
    }
}

// ---------------- Kernel 2: split-bf16 3-pass MFMA GEMM + ArcFace epilogue ----------------
// C = Ah*Bh + Ah*Bl + Al*Bh (al*bl term ~2^-16 relative, dropped)
__global__ __launch_bounds__(256, 2) void gemm_kernel(
    const unsigned short* __restrict__ Ah, const unsigned short* __restrict__ Al,
    const unsigned short* __restrict__ WhM, const unsigned short* __restrict__ WlM,
    const unsigned short* __restrict__ WhL, const unsigned short* __restrict__ WlL,
    const float* __restrict__ inv_w, const int* __restrict__ label,
    float* __restrict__ out_ml, float* __restrict__ out_cos)
{
    __shared__ __align__(16) unsigned short Ash[TILE_EL];
    __shared__ __align__(16) unsigned short Asl[TILE_EL];
    __shared__ __align__(16) unsigned short Bsh[TILE_EL];
    __shared__ __align__(16) unsigned short Bsl[TILE_EL];

    // bijective XCD swizzle (nwg = 1564 = 8*195 + 4; m204 formula: q=195, r=4)
    int lin = blockIdx.x;
    int xcd = lin & 7, pos = lin >> 3;
    int swz = (xcd < 4 ? xcd * 196 : 784 + (xcd - 4) * 195) + pos;
    // descending tile order: first-read tiles = last-written by prep (max L3 hit)
    int tn = (NT - 1) - (swz >> 1);
    int tm = swz & 1;                    // consecutive pair shares the B panel (same XCD)

    const int tid  = threadIdx.x;
    const int wid  = tid >> 6, lane = tid & 63;
    const int wm   = wid >> 1, wn   = wid & 1;
    const int lr   = lane & 15, lc  = lane >> 4;

    const unsigned short* ah0 = Ah + (size_t)tm * COMP_TILE;
    const unsigned short* al0 = Al + (size_t)tm * COMP_TILE;
    const unsigned short* bh0 = (tn == NT-1) ? WhL : WhM + (size_t)tn * COMP_TILE;
    const unsigned short* bl0 = (tn == NT-1) ? WlL : WlM + (size_t)tn * COMP_TILE;

    f32x4 acc[4][4];
    #pragma unroll
    for (int i = 0; i < 4; ++i)
        #pragma unroll
        for (int j = 0; j < 4; ++j)
            acc[i][j] = f32x4{0.f, 0.f, 0.f, 0.f};

    int aoff[4], boff[4];
    #pragma unroll
    for (int i = 0; i < 4; ++i) {
        aoff[i] = swz_off(wm * 64 + i * 16 + lr, lc);
        boff[i] = swz_off(wn * 64 + i * 16 + lr, lc);
    }

    for (int tk = 0; tk < KT; ++tk) {
        const unsigned short* ga  = ah0 + tk * TILE_EL;
        const unsigned short* gal = al0 + tk * TILE_EL;
        const unsigned short* gb  = bh0 + tk * TILE_EL;
        const unsigned short* gbl = bl0 + tk * TILE_EL;
        __syncthreads();                          // prev-iter LDS readers done
        GLL16(ga  + tid * 8,        &Ash[tid * 8]);
        GLL16(ga  + 2048 + tid * 8, &Ash[2048 + tid * 8]);
        GLL16(gal + tid * 8,        &Asl[tid * 8]);
        GLL16(gal + 2048 + tid * 8, &Asl[2048 + tid * 8]);
        GLL16(gb  + tid * 8,        &Bsh[tid * 8]);
        GLL16(gb  + 2048 + tid * 8, &Bsh[2048 + tid * 8]);
        GLL16(gbl + tid * 8,        &Bsl[tid * 8]);
        GLL16(gbl + 2048 + tid * 8, &Bsl[2048 + tid * 8]);
        __syncthreads();                          // compiler drains vmcnt(0) before barrier

        short8 fah[4], fal[4], fbh[4], fbl[4];
        #pragma unroll
        for (int i = 0; i < 4; ++i) {
            fah[i] = *(const short8*)&Ash[aoff[i]];
            fal[i] = *(const short8*)&Asl[aoff[i]];
            fbh[i] = *(const short8*)&Bsh[boff[i]];
            fbl[i] = *(const short8*)&Bsl[boff[i]];
        }
        #pragma unroll
        for (int i = 0; i < 4; ++i)
            #pragma unroll
            for (int j = 0; j < 4; ++j) {
                acc[i][j] = __builtin_amdgcn_mfma_f32_16x16x32_bf16(fah[i], fbh[j], acc[i][j], 0, 0, 0);
                acc[i][j] = __builtin_amdgcn_mfma_f32_16x16x32_bf16(fah[i], fbl[j], acc[i][j], 0, 0, 0);
                acc[i][j] = __builtin_amdgcn_mfma_f32_16x16x32_bf16(fal[i], fbh[j], acc[i][j], 0, 0, 0);
            }
    }

    // ---- epilogue: cos = acc*inv_w[n]; margin only where n == label[m] ----
    const int n0  = tn * 128 + wn * 64;
    const int m0g = tm * 128 + wm * 64;
    float invw[4]; int ncol[4]; bool nok[4];
    #pragma unroll
    for (int j = 0; j < 4; ++j) {
        ncol[j] = n0 + j * 16 + lr;
        nok[j]  = (ncol[j] < Cc);
        invw[j] = nok[j] ? inv_w[ncol[j]] : 0.0f;
    }
    #pragma unroll
    for (int i = 0; i < 4; ++i) {
        #pragma unroll
        for (int r = 0; r < 4; ++r) {
            int m = m0g + i * 16 + lc * 4 + r;    // C/D: row=(lane>>4)*4+reg, col=lane&15
            int lab = label[m];
            size_t base = (size_t)m * Cc;
            #pragma unroll
            for (int j = 0; j < 4; ++j) {
                float cosv = acc[i][j][r] * invw[j];
                float sc = SCALE * cosv;
                float ml = sc;
                if (ncol[j] == lab) {
                    if (cosv > THRESH) {
                        float sint = sqrtf(fmaxf(0.f, 1.f - cosv * cosv));
                        ml = SCALE * (cosv * COS_M - sint * SIN_M);
                    } else {
                        ml = SCALE * (cosv - MARGIN * SIN_M);
                    }
                }
                if (nok[j]) {
                    __builtin_nontemporal_store(ml, out_ml  + base + ncol[j]);  // nt: never re-read
                    __builtin_nontemporal_store(sc, out_cos + base + ncol[j]);
                }
            }
        }
    }
}

extern "C" void kernel_launch(void* const* d_in, const int* in_sizes, int n_in,
                              void* d_out, int out_size, void* d_ws, size_t ws_size,
                              hipStream_t stream) {
    const float* feat  = (const float*)d_in[0];
    const float* W     = (const float*)d_in[1];
    const int*   label = (const int*)d_in[2];

    float* out     = (float*)d_out;
    float* out_ml  = out;
    float* out_cos = out + (size_t)Bsz * Cc;
    float* out_w   = out + (size_t)2 * Bsz * Cc;

    char* ws = (char*)d_ws;
    float* inv_w = (float*)ws;
    size_t off = (size_t)Cc * 4;                       // 400000 B (16B-aligned)
    unsigned short* Ah = (unsigned short*)(ws + off); off += (size_t)2 * COMP_TILE * 2;
    unsigned short* Al = (unsigned short*)(ws + off); off += (size_t)2 * COMP_TILE * 2;

    const size_t wsplit_bytes = (size_t)2 * NT * COMP_TILE * 2;   // ~205 MB
    bool big = ws_size >= off + wsplit_bytes;

    unsigned short *whM, *wlM, *whL, *wlL;
    float* w_copy;
    if (big) {
        whM = (unsigned short*)(ws + off);
        wlM = whM + (size_t)NT * COMP_TILE;
        whL = whM + (size_t)(NT - 1) * COMP_TILE;     // alias: last-tile slot of whM
        wlL = wlM + (size_t)(NT - 1) * COMP_TILE;     // alias: last-tile slot of wlM
        w_copy = out_w;                                // write fp32 copy directly
    } else {
        whM = (unsigned short*)out_w;                  // tiles 0..780 live in out_w (204.73 MB)
        wlM = whM + (size_t)(NT - 1) * COMP_TILE;
        whL = (unsigned short*)(ws + off); off += (size_t)COMP_TILE * 2;
        wlL = (unsigned short*)(ws + off); off += (size_t)COMP_TILE * 2;
        w_copy = nullptr;                              // out_w rewritten by async d2d copy below
    }

    hipLaunchKernelGGL(prep_kernel, dim3(Cc / 4), dim3(256), 0, stream,
                       W, feat, inv_w, w_copy, whM, wlM, whL, wlL, Ah, Al);
    hipLaunchKernelGGL(gemm_kernel, dim3(2 * NT), dim3(256), 0, stream,
                       Ah, Al, whM, wlM, whL, wlL, inv_w, label, out_ml, out_cos);
    if (!big) {
        hipMemcpyAsync(out_w, W, (size_t)Cc * Dd * sizeof(float),
                       hipMemcpyDeviceToDevice, stream);
    }
}